// Round 14
// baseline (1787.292 us; speedup 1.0000x reference)
//
#include <hip/hip_runtime.h>
#include <math.h>

#define M_TOK 8192
#define D_DIM 2048
#define G_GENES 4096
#define GD_DIM 256
#define KSEL 32
#define NCAND 40
#define NSLICE 8

typedef float f32x4 __attribute__((ext_vector_type(4)));
typedef short bf16x8 __attribute__((ext_vector_type(8)));

__device__ __forceinline__ void async_copy16(const void* g, void* lds) {
  __builtin_amdgcn_global_load_lds((const __attribute__((address_space(1))) void*)g,
                                   (__attribute__((address_space(3))) void*)lds, 16, 0, 0);
}

__device__ __forceinline__ unsigned short f2bf(float f) {
  unsigned int u = __float_as_uint(f);
  unsigned int r = (u + 0x7fffu + ((u >> 16) & 1u)) >> 16;
  return (unsigned short)r;
}
__device__ __forceinline__ float bf2f(unsigned short h) {
  return __uint_as_float(((unsigned int)h) << 16);
}

// ---------------- K1: RMSNorm -> r[t], xn_bf16 ----------------
__global__ __launch_bounds__(256) void k1_rmsnorm(const float* __restrict__ x,
                                                  const float* __restrict__ nw,
                                                  float* __restrict__ r_out,
                                                  unsigned short* __restrict__ xn_bf) {
  int t = blockIdx.x, tid = threadIdx.x;
  const float4* xr = (const float4*)(x + (size_t)t * D_DIM);
  float4 a = xr[tid], b = xr[tid + 256];
  double ss = (double)a.x*a.x + (double)a.y*a.y + (double)a.z*a.z + (double)a.w*a.w
            + (double)b.x*b.x + (double)b.y*b.y + (double)b.z*b.z + (double)b.w*b.w;
  for (int off = 32; off; off >>= 1) ss += __shfl_down(ss, off);
  __shared__ double sred[4];
  __shared__ float rshare;
  int lane = tid & 63, wv = tid >> 6;
  if (lane == 0) sred[wv] = ss;
  __syncthreads();
  if (tid == 0) {
    double tot = sred[0] + sred[1] + sred[2] + sred[3];
    float r = (float)(1.0 / sqrt(tot / (double)D_DIM + 1.1920928955078125e-7));
    rshare = r; r_out[t] = r;
  }
  __syncthreads();
  float r = rshare;
  const float4* nw4 = (const float4*)nw;
  float4 na = nw4[tid], nb = nw4[tid + 256];
  ushort4 oa, ob;
  oa.x = f2bf(a.x * r * na.x); oa.y = f2bf(a.y * r * na.y);
  oa.z = f2bf(a.z * r * na.z); oa.w = f2bf(a.w * r * na.w);
  ob.x = f2bf(b.x * r * nb.x); ob.y = f2bf(b.y * r * nb.y);
  ob.z = f2bf(b.z * r * nb.z); ob.w = f2bf(b.w * r * nb.w);
  ushort4* o4 = (ushort4*)(xn_bf + (size_t)t * D_DIM);
  o4[tid] = oa; o4[tid + 256] = ob;
}

// ---------------- K2: Wc fp32 -> bf16 ----------------
__global__ __launch_bounds__(256) void k2_cvt(const float* __restrict__ w,
                                              unsigned short* __restrict__ wb) {
  size_t i = (size_t)blockIdx.x * 256 + threadIdx.x;   // handles 8 elements
  const float4* w4 = (const float4*)w;
  float4 a = w4[2*i], b = w4[2*i+1];
  ushort4 oa, ob;
  oa.x = f2bf(a.x); oa.y = f2bf(a.y); oa.z = f2bf(a.z); oa.w = f2bf(a.w);
  ob.x = f2bf(b.x); ob.y = f2bf(b.y); ob.z = f2bf(b.z); ob.w = f2bf(b.w);
  ((ushort4*)wb)[2*i] = oa; ((ushort4*)wb)[2*i+1] = ob;
}

// ---------------- K2b: split Wd/Wu into bf16 hi+lo ----------------
__global__ __launch_bounds__(256) void k2b_split(const float* __restrict__ wd,
                                                 const float* __restrict__ wu,
                                                 unsigned short* __restrict__ wdh,
                                                 unsigned short* __restrict__ wdl,
                                                 unsigned short* __restrict__ wuh,
                                                 unsigned short* __restrict__ wul) {
  const float* src = blockIdx.y ? wu : wd;
  unsigned short* dh = blockIdx.y ? wuh : wdh;
  unsigned short* dl = blockIdx.y ? wul : wdl;
  size_t i = (size_t)blockIdx.x * 256 + threadIdx.x;   // float4 index
  float4 v = ((const float4*)src)[i];
  ushort4 h, l;
  h.x = f2bf(v.x); l.x = f2bf(v.x - bf2f(h.x));
  h.y = f2bf(v.y); l.y = f2bf(v.y - bf2f(h.y));
  h.z = f2bf(v.z); l.z = f2bf(v.z - bf2f(h.z));
  h.w = f2bf(v.w); l.w = f2bf(v.w - bf2f(h.w));
  ((ushort4*)dh)[i] = h;
  ((ushort4*)dl)[i] = l;
}

// ---------------- K3: logits GEMM, 256x256 tile, 8-wave, ring-2 / 2-blocks-per-CU ----------------
// BK=32, ring-2 LDS (64 KB -> 2 blocks/CU). T3-minimal schedule, verbatim:
// per K-tile: {STAGE(t+1 -> other buf) -> 12x ds_read(cur) -> lgkmcnt(0) ->
// setprio(1) 32 MFMA setprio(0) -> vmcnt(0) -> ONE barrier}. Drain-0 stall is
// hidden by the co-resident block's MFMA (m114 cross-block overlap); barrier
// count halved vs R10. Race-free: all waves' ds_reads of buf[cur] retire before
// the barrier, so next iter's stage into buf[cur] cannot clobber live reads.
// Accumulation order identical -> bit-identical logits.
__global__ __launch_bounds__(512, 4) void k3_gemm_logits(const unsigned short* __restrict__ A,
                                                         const unsigned short* __restrict__ B,
                                                         unsigned short* __restrict__ C) {
  __shared__ unsigned short As[2][256 * 32];
  __shared__ unsigned short Bs[2][256 * 32];
  const int tid = threadIdx.x;
  const int lane = tid & 63, wv = tid >> 6;
  const int wm = wv >> 2, wn = wv & 3;       // wave tile: 128(M) x 64(N)
  int lin = blockIdx.x;
  int swz = (lin & 7) * 64 + (lin >> 3);
  const int bm = swz & 31, bn = swz >> 5;

  const int grow = lane >> 2;                          // 0..15 within 16-row issue
  const int gslot = (lane & 3) ^ ((lane >> 3) & 3);    // pre-swizzled global slot
  const unsigned short* agp = A + (size_t)(bm * 256 + wv * 32 + grow) * D_DIM + gslot * 8;
  const unsigned short* bgp = B + (size_t)(bn * 256 + wv * 32 + grow) * D_DIM + gslot * 8;
  const int fr = lane & 15;
  const int sw8 = (((lane >> 4) ^ ((lane >> 1) & 3))) * 8;  // swizzled 16B slot * 8 ushorts

  f32x4 acc[8][4];
#pragma unroll
  for (int m = 0; m < 8; ++m)
#pragma unroll
    for (int n = 0; n < 4; ++n) acc[m][n] = (f32x4){0.f, 0.f, 0.f, 0.f};

#define STAGE_AB(t_, b_) { const int kt_ = (t_) * 32;                                \
    async_copy16(agp + kt_,              &As[b_][(wv * 32) * 32]);                   \
    async_copy16(agp + kt_ + 16 * D_DIM, &As[b_][(wv * 32 + 16) * 32]);              \
    async_copy16(bgp + kt_,              &Bs[b_][(wv * 32) * 32]);                   \
    async_copy16(bgp + kt_ + 16 * D_DIM, &Bs[b_][(wv * 32 + 16) * 32]); }

#define BODY(t_) {                                                                   \
    const int cb_ = (t_) & 1;                                                        \
    if ((t_) + 1 < 64) STAGE_AB((t_) + 1, cb_ ^ 1);                                  \
    const unsigned short* as_ = As[cb_];                                             \
    const unsigned short* bs_ = Bs[cb_];                                             \
    bf16x8 fa_[8], fb_[4];                                                           \
    _Pragma("unroll") for (int n = 0; n < 4; ++n)                                    \
      fb_[n] = *(const bf16x8*)&bs_[(wn * 64 + n * 16 + fr) * 32 + sw8];             \
    _Pragma("unroll") for (int m = 0; m < 8; ++m)                                    \
      fa_[m] = *(const bf16x8*)&as_[(wm * 128 + m * 16 + fr) * 32 + sw8];            \
    asm volatile("s_waitcnt lgkmcnt(0)" ::: "memory");                               \
    __builtin_amdgcn_sched_barrier(0);                                               \
    __builtin_amdgcn_s_setprio(1);                                                   \
    _Pragma("unroll") for (int m = 0; m < 4; ++m)                                    \
      _Pragma("unroll") for (int n = 0; n < 4; ++n)                                  \
        acc[m][n] = __builtin_amdgcn_mfma_f32_16x16x32_bf16(fa_[m], fb_[n], acc[m][n], 0, 0, 0); \
    _Pragma("unroll") for (int m = 0; m < 4; ++m)                                    \
      _Pragma("unroll") for (int n = 0; n < 4; ++n)                                  \
        acc[m + 4][n] = __builtin_amdgcn_mfma_f32_16x16x32_bf16(fa_[m + 4], fb_[n], acc[m + 4][n], 0, 0, 0); \
    __builtin_amdgcn_s_setprio(0);                                                   \
    asm volatile("s_waitcnt vmcnt(0)" ::: "memory");                                 \
    __builtin_amdgcn_s_barrier(); }

  // prologue: stage tile 0 into buf0
  STAGE_AB(0, 0);
  asm volatile("s_waitcnt vmcnt(0)" ::: "memory");
  __builtin_amdgcn_s_barrier();

#pragma unroll 1
  for (int t = 0; t < 64; t += 2) {
    BODY(t);
    BODY(t + 1);
  }
#undef BODY
#undef STAGE_AB

#pragma unroll
  for (int m = 0; m < 8; ++m)
#pragma unroll
    for (int n = 0; n < 4; ++n)
#pragma unroll
      for (int j = 0; j < 4; ++j) {
        int row = bm * 256 + wm * 128 + m * 16 + (lane >> 4) * 4 + j;
        int col = bn * 256 + wn * 64 + n * 16 + fr;
        C[(size_t)row * G_GENES + col] = f2bf(acc[m][n][j]);
      }
}

// ---------------- K4: per-token top-40 via 16-bit radix threshold search ----------------
__global__ __launch_bounds__(256) void k4_topk(const unsigned short* __restrict__ L,
                                               int* __restrict__ cand) {
  int wv = threadIdx.x >> 6, lane = threadIdx.x & 63;
  int t = blockIdx.x * 4 + wv;
  const unsigned short* lp = L + (size_t)t * G_GENES;
  unsigned kp[32];
#pragma unroll
  for (int i = 0; i < 8; ++i) {
    uint4 raw = *(const uint4*)(lp + i * 512 + lane * 8);
    unsigned rr[4] = {raw.x, raw.y, raw.z, raw.w};
#pragma unroll
    for (int q = 0; q < 4; ++q) {
      unsigned r = rr[q];
      unsigned s = (r >> 15) & 0x00010001u;
      unsigned xm = 0x80008000u | (s * 0x7FFFu);   // per-half: sign? 0xFFFF : 0x8000
      kp[i * 4 + q] = r ^ xm;
    }
  }
  unsigned lo = 0, hi = 65536;
  while (hi - lo > 1u) {
    unsigned mid = (lo + hi) >> 1;
    int c = 0;
#pragma unroll
    for (int q = 0; q < 32; ++q) {
      c += __popcll(__ballot((kp[q] & 0xFFFFu) >= mid));
      c += __popcll(__ballot((kp[q] >> 16) >= mid));
    }
    if (c >= NCAND) lo = mid; else hi = mid;
  }
  const unsigned T = lo;
  unsigned long long below = (1ull << lane) - 1ull;
  int* outp = cand + (size_t)t * NCAND;
  int cnt = 0;
#pragma unroll
  for (int q = 0; q < 32; ++q) {
#pragma unroll
    for (int h = 0; h < 2; ++h) {
      unsigned key = h ? (kp[q] >> 16) : (kp[q] & 0xFFFFu);
      bool pred = key > T;
      unsigned long long m = __ballot(pred);
      if (pred) {
        int pos = cnt + (int)__popcll(m & below);
        outp[pos] = (q >> 2) * 512 + lane * 8 + (q & 3) * 2 + h;
      }
      cnt += (int)__popcll(m);
    }
  }
#pragma unroll 1
  for (int q = 0; q < 32 && cnt < NCAND; ++q) {
#pragma unroll
    for (int h = 0; h < 2; ++h) {
      unsigned key = h ? (kp[q] >> 16) : (kp[q] & 0xFFFFu);
      bool pred = key == T;
      unsigned long long m = __ballot(pred);
      if (pred) {
        int pos = cnt + (int)__popcll(m & below);
        if (pos < NCAND)
          outp[pos] = (q >> 2) * 512 + lane * 8 + (q & 3) * 2 + h;
      }
      cnt += (int)__popcll(m);
    }
  }
}

// ---------------- K5a: fp64 partial rescore, D-sliced, compress-tree reduce ----------------
__global__ __launch_bounds__(256) void k5a_partial(const float* __restrict__ x,
                                                   const float* __restrict__ r,
                                                   const float* __restrict__ nw,
                                                   const float* __restrict__ Wc,
                                                   const int* __restrict__ cand,
                                                   double* __restrict__ part) {
  int bid = blockIdx.x;
  int slice = bid & 7;
  int group = bid >> 3;
  int wv = threadIdx.x >> 6, lane = threadIdx.x & 63;
  const int dbase = slice * 256;
  float4 nv = *(const float4*)(nw + dbase + lane * 4);
  bool b0 = (lane & 1) != 0, b1 = (lane & 2) != 0, b2 = (lane & 4) != 0;
#pragma unroll 1
  for (int tt = 0; tt < 2; ++tt) {
    int t = group * 8 + wv * 2 + tt;
    float rr = r[t];
    float4 xv = *(const float4*)(x + (size_t)t * D_DIM + dbase + lane * 4);
    float4 xl;
    xl.x = xv.x * rr * nv.x;
    xl.y = xv.y * rr * nv.y;
    xl.z = xv.z * rr * nv.z;
    xl.w = xv.w * rr * nv.w;
    int myg = cand[t * NCAND + (lane < NCAND ? lane : 0)];
    double* outp = part + ((size_t)t * NSLICE + slice) * NCAND;
#pragma unroll 1
    for (int j0 = 0; j0 < NCAND; j0 += 8) {
      float4 w[8];
#pragma unroll
      for (int c = 0; c < 8; ++c) {
        int g = __shfl(myg, j0 + c);
        w[c] = *(const float4*)(Wc + (size_t)g * D_DIM + dbase + lane * 4);
      }
      double s[8];
#pragma unroll
      for (int c = 0; c < 8; ++c)
        s[c] = ((double)xl.x * (double)w[c].x + (double)xl.y * (double)w[c].y)
             + ((double)xl.z * (double)w[c].z + (double)xl.w * (double)w[c].w);
      // stage A (bit0): 8 -> 4 regs
      double u01 = b0 ? s[1] : s[0], t01 = b0 ? s[0] : s[1];
      double u23 = b0 ? s[3] : s[2], t23 = b0 ? s[2] : s[3];
      double u45 = b0 ? s[5] : s[4], t45 = b0 ? s[4] : s[5];
      double u67 = b0 ? s[7] : s[6], t67 = b0 ? s[6] : s[7];
      u01 += __shfl_xor(t01, 1);
      u23 += __shfl_xor(t23, 1);
      u45 += __shfl_xor(t45, 1);
      u67 += __shfl_xor(t67, 1);
      // stage B (bit1): 4 -> 2 regs
      double v03 = b1 ? u23 : u01, t03 = b1 ? u01 : u23;
      double v47 = b1 ? u67 : u45, t47 = b1 ? u45 : u67;
      v03 += __shfl_xor(t03, 2);
      v47 += __shfl_xor(t47, 2);
      // stage C (bit2): 2 -> 1 reg; lane l holds candidate (l&7) group-sum
      double wsum = b2 ? v47 : v03, t07 = b2 ? v03 : v47;
      wsum += __shfl_xor(t07, 4);
      // stages D-F: reduce across 8-lane groups
      wsum += __shfl_xor(wsum, 8);
      wsum += __shfl_xor(wsum, 16);
      wsum += __shfl_xor(wsum, 32);
      if (lane < 8) outp[j0 + lane] = wsum;
    }
  }
}

// ---------------- K6: sum partials, select top-32, softmax, combine ----------------
__global__ __launch_bounds__(256) void k6_express(const double* __restrict__ part,
                                                  const int* __restrict__ cand,
                                                  const float* __restrict__ genes,
                                                  const float* __restrict__ temp,
                                                  unsigned short* __restrict__ e_hi,
                                                  unsigned short* __restrict__ e_lo) {
  int t = blockIdx.x, tid = threadIdx.x;
  __shared__ double sval[NCAND];
  __shared__ int sidx[NCAND];
  __shared__ float sw[NCAND];
  float tclamp = fmaxf(temp[0], 0.1f);
  if (tid < NCAND) {
    const double* pp = part + (size_t)t * NSLICE * NCAND + tid;
    double v = 0.0;
#pragma unroll
    for (int s = 0; s < NSLICE; ++s) v += pp[s * NCAND];
    sval[tid] = v / (double)tclamp;
    sidx[tid] = cand[(size_t)t * NCAND + tid];
  }
  __syncthreads();
  if (tid < 64) {
    double v = (tid < NCAND) ? sval[tid] : -1.0e300;
    int gi = (tid < NCAND) ? sidx[tid] : 0x7fffffff;
    int rank = 0;
    for (int j = 0; j < NCAND; ++j) {
      double vj = sval[j]; int gj = sidx[j];
      if (vj > v || (vj == v && gj < gi)) rank++;
    }
    bool sel = (tid < NCAND) && (rank < KSEL);
    double vs = sel ? v : -1.0e300;
    double mx = vs;
    for (int off = 32; off; off >>= 1) { double o = __shfl_xor(mx, off); mx = fmax(mx, o); }
    double e = sel ? exp(v - mx) : 0.0;
    double ssum = e;
    for (int off = 32; off; off >>= 1) ssum += __shfl_xor(ssum, off);
    if (tid < NCAND) sw[tid] = (float)(e / ssum);
  }
  __syncthreads();
  float a0 = 0.f, a1 = 0.f, a2 = 0.f, a3 = 0.f;
#pragma unroll
  for (int k = 0; k < NCAND; k += 4) {
    a0 += sw[k]     * genes[(size_t)sidx[k]     * GD_DIM + tid];
    a1 += sw[k + 1] * genes[(size_t)sidx[k + 1] * GD_DIM + tid];
    a2 += sw[k + 2] * genes[(size_t)sidx[k + 2] * GD_DIM + tid];
    a3 += sw[k + 3] * genes[(size_t)sidx[k + 3] * GD_DIM + tid];
  }
  float acc = (a0 + a1) + (a2 + a3);
  unsigned short h = f2bf(acc);
  unsigned short l = f2bf(acc - bf2f(h));
  e_hi[(size_t)t * GD_DIM + tid] = h;
  e_lo[(size_t)t * GD_DIM + tid] = l;
}

// ---------------- K7: bf16-split MFMA down/up GEMM (R9 two-phase version, best-known) ----------------
__global__ __launch_bounds__(512, 1) void k7_mfma(const unsigned short* __restrict__ e_hi,
                                                  const unsigned short* __restrict__ e_lo,
                                                  const unsigned short* __restrict__ wdh,
                                                  const unsigned short* __restrict__ wdl,
                                                  const unsigned short* __restrict__ wuh,
                                                  const unsigned short* __restrict__ wul,
                                                  const float* __restrict__ x,
                                                  const float* __restrict__ r,
                                                  const float* __restrict__ nw,
                                                  const float* __restrict__ scale_p,
                                                  float* __restrict__ out) {
  __shared__ unsigned short L[3][6][128 * 32];   // 144 KB: comp 0=Ah 1=Al 2=Dh 3=Dl 4=Uh 5=Ul
  const int tid = threadIdx.x;
  const int lane = tid & 63, wv = tid >> 6;
  const int wm = wv >> 2, wn = wv & 3;           // wave tile 64(M) x 32(N)
  int lin = blockIdx.x;
  int swz = (lin & 7) * 128 + (lin >> 3);        // bijective XCD swizzle (1024 % 8 == 0)
  const int bm = swz & 63, bn = swz >> 6;

  const int grow = lane >> 2;
  const int gslot = (lane & 3) ^ ((lane >> 3) & 3);
  const int goff = gslot * 8;
  const unsigned short* ehp = e_hi + (size_t)(bm * 128 + wv * 16 + grow) * GD_DIM + goff;
  const unsigned short* elp = e_lo + (size_t)(bm * 128 + wv * 16 + grow) * GD_DIM + goff;
  const unsigned short* dhp = wdh + (size_t)(bn * 128 + wv * 16 + grow) * GD_DIM + goff;
  const unsigned short* dlp = wdl + (size_t)(bn * 128 + wv * 16 + grow) * GD_DIM + goff;
  const unsigned short* uhp = wuh + (size_t)(bn * 128 + wv * 16 + grow) * GD_DIM + goff;
  const unsigned short* ulp = wul + (size_t)(bn * 128 + wv * 16 + grow) * GD_DIM + goff;
  const int ldst = (wv * 16) * 32;               // this wave's 16-row chunk (lds elems)

  const int fr = lane & 15;
  const int sw8 = ((lane >> 4) ^ ((lane >> 1) & 3)) * 8;

  f32x4 accD[4][2], accU[4][2];
#pragma unroll
  for (int m = 0; m < 4; ++m)
#pragma unroll
    for (int n = 0; n < 2; ++n) {
      accD[m][n] = (f32x4){0.f, 0.f, 0.f, 0.f};
      accU[m][n] = (f32x4){0.f, 0.f, 0.f, 0.f};
    }

#define STAGE7(t_) if ((t_) < 8) { const int b_ = (t_) % 3; const int kt_ = (t_) * 32; \
    async_copy16(ehp + kt_, &L[b_][0][ldst]); \
    async_copy16(elp + kt_, &L[b_][1][ldst]); \
    async_copy16(dhp + kt_, &L[b_][2][ldst]); \
    async_copy16(dlp + kt_, &L[b_][3][ldst]); \
    async_copy16(uhp + kt_, &L[b_][4][ldst]); \
    async_copy16(ulp + kt_, &L[b_][5][ldst]); }

  STAGE7(0); STAGE7(1);
  asm volatile("s_waitcnt vmcnt(6)" ::: "memory");
  __builtin_amdgcn_s_barrier();

#pragma unroll 1
  for (int t = 0; t < 8; ++t) {
    const int b = t % 3;
    bf16x8 fah[4], fal[4], fh[2], fl[2];
    // ---- phase 1: D-quadrant ----
#pragma unroll
    for (int m = 0; m < 4; ++m) {
      int off = (wm * 64 + m * 16 + fr) * 32 + sw8;
      fah[m] = *(const bf16x8*)&L[b][0][off];
      fal[m] = *(const bf16x8*)&L[b][1][off];
    }
#pragma unroll
    for (int n = 0; n < 2; ++n) {
      int off = (wn * 32 + n * 16 + fr) * 32 + sw8;
      fh[n] = *(const bf16x8*)&L[b][2][off];
      fl[n] = *(const bf16x8*)&L[b][3][off];
    }
    STAGE7(t + 2);
    __builtin_amdgcn_s_barrier();
    asm volatile("s_waitcnt lgkmcnt(0)" ::: "memory");
    __builtin_amdgcn_sched_barrier(0);
    __builtin_amdgcn_s_setprio(1);
#pragma unroll
    for (int m = 0; m < 4; ++m)
#pragma unroll
      for (int n = 0; n < 2; ++n) {
        accD[m][n] = __builtin_amdgcn_mfma_f32_16x16x32_bf16(fah[m], fh[n], accD[m][n], 0, 0, 0);
        accD[m][n] = __builtin_amdgcn_mfma_f32_16x16x32_bf16(fah[m], fl[n], accD[m][n], 0, 0, 0);
        accD[m][n] = __builtin_amdgcn_mfma_f32_16x16x32_bf16(fal[m], fh[n], accD[m][n], 0, 0, 0);
      }
    __builtin_amdgcn_s_setprio(0);
    __builtin_amdgcn_s_barrier();
    // ---- phase 2: U-quadrant (fah/fal reused) ----
#pragma unroll
    for (int n = 0; n < 2; ++n) {
      int off = (wn * 32 + n * 16 + fr) * 32 + sw8;
      fh[n] = *(const bf16x8*)&L[b][4][off];
      fl[n] = *(const bf16x8*)&L[b][5][off];
    }
    __builtin_amdgcn_s_barrier();
    asm volatile("s_waitcnt lgkmcnt(0)" ::: "memory");
    __builtin_amdgcn_sched_barrier(0);
    __builtin_amdgcn_s_setprio(1);
#pragma unroll
    for (int m = 0; m < 4; ++m)
#pragma unroll
      for (int n = 0; n < 2; ++n) {
        accU[m][n] = __builtin_amdgcn_mfma_f32_16x16x32_bf16(fah[m], fh[n], accU[m][n], 0, 0, 0);
        accU[m][n] = __builtin_amdgcn_mfma_f32_16x16x32_bf16(fah[m], fl[n], accU[m][n], 0, 0, 0);
        accU[m][n] = __builtin_amdgcn_mfma_f32_16x16x32_bf16(fal[m], fh[n], accU[m][n], 0, 0, 0);
      }
    __builtin_amdgcn_s_setprio(0);
    if (t <= 5)      { asm volatile("s_waitcnt vmcnt(6)" ::: "memory"); }
    else if (t == 6) { asm volatile("s_waitcnt vmcnt(0)" ::: "memory"); }
    __builtin_amdgcn_s_barrier();
  }
#undef STAGE7

  float sc = scale_p[0];
#pragma unroll
  for (int m = 0; m < 4; ++m)
#pragma unroll
    for (int j = 0; j < 4; ++j) {
      int token = bm * 128 + wm * 64 + m * 16 + (lane >> 4) * 4 + j;
      float rr = r[token];
#pragma unroll
      for (int n = 0; n < 2; ++n) {
        int d = bn * 128 + wn * 32 + n * 16 + fr;
        float xn = x[(size_t)token * D_DIM + d] * rr * nw[d];
        out[(size_t)token * D_DIM + d] = tanhf(accD[m][n][j]) * xn * accU[m][n][j] * sc;
      }
    }
}

extern "C" void kernel_launch(void* const* d_in, const int* in_sizes, int n_in,
                              void* d_out, int out_size, void* d_ws, size_t ws_size,
                              hipStream_t stream) {
  const float* x       = (const float*)d_in[0];
  const float* Wc      = (const float*)d_in[1];
  const float* temp    = (const float*)d_in[2];
  const float* genes   = (const float*)d_in[3];
  const float* Wd      = (const float*)d_in[4];
  const float* Wu      = (const float*)d_in[5];
  const float* nw      = (const float*)d_in[6];
  const float* scale_p = (const float*)d_in[7];

  char* ws = (char*)d_ws;
  float* r_buf          = (float*)ws;                                   // 32 KB (64 KB reserved)
  unsigned short* xn_bf = (unsigned short*)(ws + 65536);                // 32 MB (free after k3)
  unsigned short* wc_bf = (unsigned short*)(ws + 65536 + (size_t)M_TOK * D_DIM * 2);   // 16 MB
  char* p = ws + 65536 + (size_t)M_TOK * D_DIM * 2 + (size_t)G_GENES * D_DIM * 2;
  int* cand    = (int*)p;                       p += (size_t)M_TOK * NCAND * 4;
  p += (size_t)M_TOK * NCAND * 8;               // (former cval slot, unused)
  unsigned short* e_hi = (unsigned short*)p;    p += (size_t)M_TOK * GD_DIM * 2;
  unsigned short* e_lo = (unsigned short*)p;

  // Wd/Wu bf16 hi/lo splits live in the xn_bf region (dead after k3): 4 x 1 MB
  unsigned short* wdh = (unsigned short*)(ws + 65536);
  unsigned short* wdl = wdh + (size_t)D_DIM * GD_DIM;
  unsigned short* wuh = wdl + (size_t)D_DIM * GD_DIM;
  unsigned short* wul = wuh + (size_t)D_DIM * GD_DIM;
  // fp64 partials also in the dead xn_bf region, after the 4 MB of splits:
  double* part = (double*)(ws + 65536 + 4ull * D_DIM * GD_DIM * 2);

  unsigned short* logits_bf = (unsigned short*)d_out;  // 33.5M bf16 == 64 MB == d_out

  k1_rmsnorm<<<dim3(M_TOK), dim3(256), 0, stream>>>(x, nw, r_buf, xn_bf);
  k2_cvt<<<dim3((G_GENES * D_DIM) / (256 * 8)), dim3(256), 0, stream>>>(Wc, wc_bf);
  k3_gemm_logits<<<dim3((M_TOK / 256) * (G_GENES / 256)), dim3(512), 0, stream>>>(xn_bf, wc_bf, logits_bf);
  k4_topk<<<dim3(M_TOK / 4), dim3(256), 0, stream>>>(logits_bf, cand);
  k2b_split<<<dim3((D_DIM * GD_DIM) / (256 * 4), 2), dim3(256), 0, stream>>>(Wd, Wu, wdh, wdl, wuh, wul);
  k5a_partial<<<dim3(M_TOK), dim3(256), 0, stream>>>(x, r_buf, nw, Wc, cand, part);
  k6_express<<<dim3(M_TOK), dim3(256), 0, stream>>>(part, cand, genes, temp, e_hi, e_lo);
  k7_mfma<<<dim3((M_TOK / 128) * (D_DIM / 128)), dim3(512), 0, stream>>>(e_hi, e_lo, wdh, wdl, wuh, wul,
                                                                         x, r_buf, nw, scale_p, (float*)d_out);
}

// Round 15
// 446.708 us; speedup vs baseline: 4.0010x; 4.0010x over previous
//
#include <hip/hip_runtime.h>
#include <math.h>

#define M_TOK 8192
#define D_DIM 2048
#define G_GENES 4096
#define GD_DIM 256
#define KSEL 32
#define NCAND 40
#define NSLICE 8

typedef float f32x4 __attribute__((ext_vector_type(4)));
typedef short bf16x8 __attribute__((ext_vector_type(8)));

__device__ __forceinline__ void async_copy16(const void* g, void* lds) {
  __builtin_amdgcn_global_load_lds((const __attribute__((address_space(1))) void*)g,
                                   (__attribute__((address_space(3))) void*)lds, 16, 0, 0);
}

__device__ __forceinline__ unsigned short f2bf(float f) {
  unsigned int u = __float_as_uint(f);
  unsigned int r = (u + 0x7fffu + ((u >> 16) & 1u)) >> 16;
  return (unsigned short)r;
}
__device__ __forceinline__ float bf2f(unsigned short h) {
  return __uint_as_float(((unsigned int)h) << 16);
}

// ---------------- K1: RMSNorm -> r[t], xn_bf16 ----------------
__global__ __launch_bounds__(256) void k1_rmsnorm(const float* __restrict__ x,
                                                  const float* __restrict__ nw,
                                                  float* __restrict__ r_out,
                                                  unsigned short* __restrict__ xn_bf) {
  int t = blockIdx.x, tid = threadIdx.x;
  const float4* xr = (const float4*)(x + (size_t)t * D_DIM);
  float4 a = xr[tid], b = xr[tid + 256];
  double ss = (double)a.x*a.x + (double)a.y*a.y + (double)a.z*a.z + (double)a.w*a.w
            + (double)b.x*b.x + (double)b.y*b.y + (double)b.z*b.z + (double)b.w*b.w;
  for (int off = 32; off; off >>= 1) ss += __shfl_down(ss, off);
  __shared__ double sred[4];
  __shared__ float rshare;
  int lane = tid & 63, wv = tid >> 6;
  if (lane == 0) sred[wv] = ss;
  __syncthreads();
  if (tid == 0) {
    double tot = sred[0] + sred[1] + sred[2] + sred[3];
    float r = (float)(1.0 / sqrt(tot / (double)D_DIM + 1.1920928955078125e-7));
    rshare = r; r_out[t] = r;
  }
  __syncthreads();
  float r = rshare;
  const float4* nw4 = (const float4*)nw;
  float4 na = nw4[tid], nb = nw4[tid + 256];
  ushort4 oa, ob;
  oa.x = f2bf(a.x * r * na.x); oa.y = f2bf(a.y * r * na.y);
  oa.z = f2bf(a.z * r * na.z); oa.w = f2bf(a.w * r * na.w);
  ob.x = f2bf(b.x * r * nb.x); ob.y = f2bf(b.y * r * nb.y);
  ob.z = f2bf(b.z * r * nb.z); ob.w = f2bf(b.w * r * nb.w);
  ushort4* o4 = (ushort4*)(xn_bf + (size_t)t * D_DIM);
  o4[tid] = oa; o4[tid + 256] = ob;
}

// ---------------- K2: Wc fp32 -> bf16 ----------------
__global__ __launch_bounds__(256) void k2_cvt(const float* __restrict__ w,
                                              unsigned short* __restrict__ wb) {
  size_t i = (size_t)blockIdx.x * 256 + threadIdx.x;   // handles 8 elements
  const float4* w4 = (const float4*)w;
  float4 a = w4[2*i], b = w4[2*i+1];
  ushort4 oa, ob;
  oa.x = f2bf(a.x); oa.y = f2bf(a.y); oa.z = f2bf(a.z); oa.w = f2bf(a.w);
  ob.x = f2bf(b.x); ob.y = f2bf(b.y); ob.z = f2bf(b.z); ob.w = f2bf(b.w);
  ((ushort4*)wb)[2*i] = oa; ((ushort4*)wb)[2*i+1] = ob;
}

// ---------------- K2b: split Wd/Wu into bf16 hi+lo ----------------
__global__ __launch_bounds__(256) void k2b_split(const float* __restrict__ wd,
                                                 const float* __restrict__ wu,
                                                 unsigned short* __restrict__ wdh,
                                                 unsigned short* __restrict__ wdl,
                                                 unsigned short* __restrict__ wuh,
                                                 unsigned short* __restrict__ wul) {
  const float* src = blockIdx.y ? wu : wd;
  unsigned short* dh = blockIdx.y ? wuh : wdh;
  unsigned short* dl = blockIdx.y ? wul : wdl;
  size_t i = (size_t)blockIdx.x * 256 + threadIdx.x;   // float4 index
  float4 v = ((const float4*)src)[i];
  ushort4 h, l;
  h.x = f2bf(v.x); l.x = f2bf(v.x - bf2f(h.x));
  h.y = f2bf(v.y); l.y = f2bf(v.y - bf2f(h.y));
  h.z = f2bf(v.z); l.z = f2bf(v.z - bf2f(h.z));
  h.w = f2bf(v.w); l.w = f2bf(v.w - bf2f(h.w));
  ((ushort4*)dh)[i] = h;
  ((ushort4*)dl)[i] = l;
}

// ---------------- K3: logits GEMM (R10 best-known: 256x256, 8-wave, single merged phase/K-tile) ----------------
// BK=32, ring-4 LDS (3 tiles prefetch ahead). Per K-tile: {12x ds_read_b128 +
// 4x global_load_lds -> barrier -> lgkmcnt(0) -> setprio(1) 32 MFMA setprio(0)
// -> counted vmcnt -> barrier}. PARKED at 145 us / 948 TF: R11 (split-batch),
// R12 (reg pipeline), R14 (ring-2 occupancy: VGPR cap -> spill catastrophe)
// all regressed. launch_bounds MUST stay (512,1): acc needs ~160 VGPR.
__global__ __launch_bounds__(512, 1) void k3_gemm_logits(const unsigned short* __restrict__ A,
                                                         const unsigned short* __restrict__ B,
                                                         unsigned short* __restrict__ C) {
  __shared__ unsigned short As[4][256 * 32];
  __shared__ unsigned short Bs[4][256 * 32];
  const int tid = threadIdx.x;
  const int lane = tid & 63, wv = tid >> 6;
  const int wm = wv >> 2, wn = wv & 3;       // wave tile: 128(M) x 64(N)
  int lin = blockIdx.x;
  int swz = (lin & 7) * 64 + (lin >> 3);
  const int bm = swz & 31, bn = swz >> 5;

  const int grow = lane >> 2;                          // 0..15 within 16-row issue
  const int gslot = (lane & 3) ^ ((lane >> 3) & 3);    // pre-swizzled global slot
  const unsigned short* agp = A + (size_t)(bm * 256 + wv * 32 + grow) * D_DIM + gslot * 8;
  const unsigned short* bgp = B + (size_t)(bn * 256 + wv * 32 + grow) * D_DIM + gslot * 8;
  const int fr = lane & 15;
  const int sw8 = (((lane >> 4) ^ ((lane >> 1) & 3))) * 8;  // swizzled 16B slot * 8 ushorts

  f32x4 acc[8][4];
#pragma unroll
  for (int m = 0; m < 8; ++m)
#pragma unroll
    for (int n = 0; n < 4; ++n) acc[m][n] = (f32x4){0.f, 0.f, 0.f, 0.f};

#define STAGE_A3(t_) { const int b_ = (t_) & 3; const int kt_ = (t_) * 32;          \
    async_copy16(agp + kt_,              &As[b_][(wv * 32) * 32]);                   \
    async_copy16(agp + kt_ + 16 * D_DIM, &As[b_][(wv * 32 + 16) * 32]); }
#define STAGE_B3(t_) { const int b_ = (t_) & 3; const int kt_ = (t_) * 32;          \
    async_copy16(bgp + kt_,              &Bs[b_][(wv * 32) * 32]);                   \
    async_copy16(bgp + kt_ + 16 * D_DIM, &Bs[b_][(wv * 32 + 16) * 32]); }

  STAGE_A3(0); STAGE_B3(0);
  STAGE_A3(1); STAGE_B3(1);
  STAGE_A3(2); STAGE_B3(2);
  asm volatile("s_waitcnt vmcnt(8)" ::: "memory");
  __builtin_amdgcn_s_barrier();

#pragma unroll 1
  for (int t = 0; t < 64; ++t) {
    const int c = t & 3;
    const unsigned short* as = As[c];
    const unsigned short* bs = Bs[c];
    bf16x8 fa[8], fb[4];
#pragma unroll
    for (int n = 0; n < 4; ++n)
      fb[n] = *(const bf16x8*)&bs[(wn * 64 + n * 16 + fr) * 32 + sw8];
#pragma unroll
    for (int m = 0; m < 8; ++m)
      fa[m] = *(const bf16x8*)&as[(wm * 128 + m * 16 + fr) * 32 + sw8];
    if (t + 3 < 64) { STAGE_A3(t + 3); STAGE_B3(t + 3); }
    __builtin_amdgcn_s_barrier();
    asm volatile("s_waitcnt lgkmcnt(0)" ::: "memory");
    __builtin_amdgcn_sched_barrier(0);
    __builtin_amdgcn_s_setprio(1);
#pragma unroll
    for (int m = 0; m < 4; ++m)
#pragma unroll
      for (int n = 0; n < 4; ++n)
        acc[m][n] = __builtin_amdgcn_mfma_f32_16x16x32_bf16(fa[m], fb[n], acc[m][n], 0, 0, 0);
#pragma unroll
    for (int m = 0; m < 4; ++m)
#pragma unroll
      for (int n = 0; n < 4; ++n)
        acc[m + 4][n] = __builtin_amdgcn_mfma_f32_16x16x32_bf16(fa[m + 4], fb[n], acc[m + 4][n], 0, 0, 0);
    __builtin_amdgcn_s_setprio(0);
    if (t <= 60)      { asm volatile("s_waitcnt vmcnt(8)" ::: "memory"); }
    else if (t == 61) { asm volatile("s_waitcnt vmcnt(4)" ::: "memory"); }
    else if (t == 62) { asm volatile("s_waitcnt vmcnt(0)" ::: "memory"); }
    __builtin_amdgcn_s_barrier();
  }
#undef STAGE_A3
#undef STAGE_B3

#pragma unroll
  for (int m = 0; m < 8; ++m)
#pragma unroll
    for (int n = 0; n < 4; ++n)
#pragma unroll
      for (int j = 0; j < 4; ++j) {
        int row = bm * 256 + wm * 128 + m * 16 + (lane >> 4) * 4 + j;
        int col = bn * 256 + wn * 64 + n * 16 + fr;
        C[(size_t)row * G_GENES + col] = f2bf(acc[m][n][j]);
      }
}

// ---------------- K4: per-token top-40 via 16-bit radix threshold search ----------------
__global__ __launch_bounds__(256) void k4_topk(const unsigned short* __restrict__ L,
                                               int* __restrict__ cand) {
  int wv = threadIdx.x >> 6, lane = threadIdx.x & 63;
  int t = blockIdx.x * 4 + wv;
  const unsigned short* lp = L + (size_t)t * G_GENES;
  unsigned kp[32];
#pragma unroll
  for (int i = 0; i < 8; ++i) {
    uint4 raw = *(const uint4*)(lp + i * 512 + lane * 8);
    unsigned rr[4] = {raw.x, raw.y, raw.z, raw.w};
#pragma unroll
    for (int q = 0; q < 4; ++q) {
      unsigned r = rr[q];
      unsigned s = (r >> 15) & 0x00010001u;
      unsigned xm = 0x80008000u | (s * 0x7FFFu);   // per-half: sign? 0xFFFF : 0x8000
      kp[i * 4 + q] = r ^ xm;
    }
  }
  unsigned lo = 0, hi = 65536;
  while (hi - lo > 1u) {
    unsigned mid = (lo + hi) >> 1;
    int c = 0;
#pragma unroll
    for (int q = 0; q < 32; ++q) {
      c += __popcll(__ballot((kp[q] & 0xFFFFu) >= mid));
      c += __popcll(__ballot((kp[q] >> 16) >= mid));
    }
    if (c >= NCAND) lo = mid; else hi = mid;
  }
  const unsigned T = lo;
  unsigned long long below = (1ull << lane) - 1ull;
  int* outp = cand + (size_t)t * NCAND;
  int cnt = 0;
#pragma unroll
  for (int q = 0; q < 32; ++q) {
#pragma unroll
    for (int h = 0; h < 2; ++h) {
      unsigned key = h ? (kp[q] >> 16) : (kp[q] & 0xFFFFu);
      bool pred = key > T;
      unsigned long long m = __ballot(pred);
      if (pred) {
        int pos = cnt + (int)__popcll(m & below);
        outp[pos] = (q >> 2) * 512 + lane * 8 + (q & 3) * 2 + h;
      }
      cnt += (int)__popcll(m);
    }
  }
#pragma unroll 1
  for (int q = 0; q < 32 && cnt < NCAND; ++q) {
#pragma unroll
    for (int h = 0; h < 2; ++h) {
      unsigned key = h ? (kp[q] >> 16) : (kp[q] & 0xFFFFu);
      bool pred = key == T;
      unsigned long long m = __ballot(pred);
      if (pred) {
        int pos = cnt + (int)__popcll(m & below);
        if (pos < NCAND)
          outp[pos] = (q >> 2) * 512 + lane * 8 + (q & 3) * 2 + h;
      }
      cnt += (int)__popcll(m);
    }
  }
}

// ---------------- K5a: fp64 partial rescore, D-sliced, compress-tree reduce ----------------
__global__ __launch_bounds__(256) void k5a_partial(const float* __restrict__ x,
                                                   const float* __restrict__ r,
                                                   const float* __restrict__ nw,
                                                   const float* __restrict__ Wc,
                                                   const int* __restrict__ cand,
                                                   double* __restrict__ part) {
  int bid = blockIdx.x;
  int slice = bid & 7;
  int group = bid >> 3;
  int wv = threadIdx.x >> 6, lane = threadIdx.x & 63;
  const int dbase = slice * 256;
  float4 nv = *(const float4*)(nw + dbase + lane * 4);
  bool b0 = (lane & 1) != 0, b1 = (lane & 2) != 0, b2 = (lane & 4) != 0;
#pragma unroll 1
  for (int tt = 0; tt < 2; ++tt) {
    int t = group * 8 + wv * 2 + tt;
    float rr = r[t];
    float4 xv = *(const float4*)(x + (size_t)t * D_DIM + dbase + lane * 4);
    float4 xl;
    xl.x = xv.x * rr * nv.x;
    xl.y = xv.y * rr * nv.y;
    xl.z = xv.z * rr * nv.z;
    xl.w = xv.w * rr * nv.w;
    int myg = cand[t * NCAND + (lane < NCAND ? lane : 0)];
    double* outp = part + ((size_t)t * NSLICE + slice) * NCAND;
#pragma unroll 1
    for (int j0 = 0; j0 < NCAND; j0 += 8) {
      float4 w[8];
#pragma unroll
      for (int c = 0; c < 8; ++c) {
        int g = __shfl(myg, j0 + c);
        w[c] = *(const float4*)(Wc + (size_t)g * D_DIM + dbase + lane * 4);
      }
      double s[8];
#pragma unroll
      for (int c = 0; c < 8; ++c)
        s[c] = ((double)xl.x * (double)w[c].x + (double)xl.y * (double)w[c].y)
             + ((double)xl.z * (double)w[c].z + (double)xl.w * (double)w[c].w);
      // stage A (bit0): 8 -> 4 regs
      double u01 = b0 ? s[1] : s[0], t01 = b0 ? s[0] : s[1];
      double u23 = b0 ? s[3] : s[2], t23 = b0 ? s[2] : s[3];
      double u45 = b0 ? s[5] : s[4], t45 = b0 ? s[4] : s[5];
      double u67 = b0 ? s[7] : s[6], t67 = b0 ? s[6] : s[7];
      u01 += __shfl_xor(t01, 1);
      u23 += __shfl_xor(t23, 1);
      u45 += __shfl_xor(t45, 1);
      u67 += __shfl_xor(t67, 1);
      // stage B (bit1): 4 -> 2 regs
      double v03 = b1 ? u23 : u01, t03 = b1 ? u01 : u23;
      double v47 = b1 ? u67 : u45, t47 = b1 ? u45 : u67;
      v03 += __shfl_xor(t03, 2);
      v47 += __shfl_xor(t47, 2);
      // stage C (bit2): 2 -> 1 reg; lane l holds candidate (l&7) group-sum
      double wsum = b2 ? v47 : v03, t07 = b2 ? v03 : v47;
      wsum += __shfl_xor(t07, 4);
      // stages D-F: reduce across 8-lane groups
      wsum += __shfl_xor(wsum, 8);
      wsum += __shfl_xor(wsum, 16);
      wsum += __shfl_xor(wsum, 32);
      if (lane < 8) outp[j0 + lane] = wsum;
    }
  }
}

// ---------------- K6: sum partials, select top-32, softmax, combine ----------------
__global__ __launch_bounds__(256) void k6_express(const double* __restrict__ part,
                                                  const int* __restrict__ cand,
                                                  const float* __restrict__ genes,
                                                  const float* __restrict__ temp,
                                                  unsigned short* __restrict__ e_hi,
                                                  unsigned short* __restrict__ e_lo) {
  int t = blockIdx.x, tid = threadIdx.x;
  __shared__ double sval[NCAND];
  __shared__ int sidx[NCAND];
  __shared__ float sw[NCAND];
  float tclamp = fmaxf(temp[0], 0.1f);
  if (tid < NCAND) {
    const double* pp = part + (size_t)t * NSLICE * NCAND + tid;
    double v = 0.0;
#pragma unroll
    for (int s = 0; s < NSLICE; ++s) v += pp[s * NCAND];
    sval[tid] = v / (double)tclamp;
    sidx[tid] = cand[(size_t)t * NCAND + tid];
  }
  __syncthreads();
  if (tid < 64) {
    double v = (tid < NCAND) ? sval[tid] : -1.0e300;
    int gi = (tid < NCAND) ? sidx[tid] : 0x7fffffff;
    int rank = 0;
    for (int j = 0; j < NCAND; ++j) {
      double vj = sval[j]; int gj = sidx[j];
      if (vj > v || (vj == v && gj < gi)) rank++;
    }
    bool sel = (tid < NCAND) && (rank < KSEL);
    double vs = sel ? v : -1.0e300;
    double mx = vs;
    for (int off = 32; off; off >>= 1) { double o = __shfl_xor(mx, off); mx = fmax(mx, o); }
    double e = sel ? exp(v - mx) : 0.0;
    double ssum = e;
    for (int off = 32; off; off >>= 1) ssum += __shfl_xor(ssum, off);
    if (tid < NCAND) sw[tid] = (float)(e / ssum);
  }
  __syncthreads();
  float a0 = 0.f, a1 = 0.f, a2 = 0.f, a3 = 0.f;
#pragma unroll
  for (int k = 0; k < NCAND; k += 4) {
    a0 += sw[k]     * genes[(size_t)sidx[k]     * GD_DIM + tid];
    a1 += sw[k + 1] * genes[(size_t)sidx[k + 1] * GD_DIM + tid];
    a2 += sw[k + 2] * genes[(size_t)sidx[k + 2] * GD_DIM + tid];
    a3 += sw[k + 3] * genes[(size_t)sidx[k + 3] * GD_DIM + tid];
  }
  float acc = (a0 + a1) + (a2 + a3);
  unsigned short h = f2bf(acc);
  unsigned short l = f2bf(acc - bf2f(h));
  e_hi[(size_t)t * GD_DIM + tid] = h;
  e_lo[(size_t)t * GD_DIM + tid] = l;
}

// ---------------- K7: bf16-split MFMA down/up GEMM (R9 two-phase version, best-known) ----------------
// Tile 128(M) x 128(N), K=256, BK=32 (8 K-tiles), ring-3 LDS (144 KB), 8 waves
// (2M x 4N, wave = 64x32). Per K-tile: phase1 = 24 D-MFMAs, phase2 = 24 U-MFMAs
// (A-frags reused). Counted vmcnt(6); both-sides XOR swizzle as in k3.
__global__ __launch_bounds__(512, 1) void k7_mfma(const unsigned short* __restrict__ e_hi,
                                                  const unsigned short* __restrict__ e_lo,
                                                  const unsigned short* __restrict__ wdh,
                                                  const unsigned short* __restrict__ wdl,
                                                  const unsigned short* __restrict__ wuh,
                                                  const unsigned short* __restrict__ wul,
                                                  const float* __restrict__ x,
                                                  const float* __restrict__ r,
                                                  const float* __restrict__ nw,
                                                  const float* __restrict__ scale_p,
                                                  float* __restrict__ out) {
  __shared__ unsigned short L[3][6][128 * 32];   // 144 KB: comp 0=Ah 1=Al 2=Dh 3=Dl 4=Uh 5=Ul
  const int tid = threadIdx.x;
  const int lane = tid & 63, wv = tid >> 6;
  const int wm = wv >> 2, wn = wv & 3;           // wave tile 64(M) x 32(N)
  int lin = blockIdx.x;
  int swz = (lin & 7) * 128 + (lin >> 3);        // bijective XCD swizzle (1024 % 8 == 0)
  const int bm = swz & 63, bn = swz >> 6;

  const int grow = lane >> 2;
  const int gslot = (lane & 3) ^ ((lane >> 3) & 3);
  const int goff = gslot * 8;
  const unsigned short* ehp = e_hi + (size_t)(bm * 128 + wv * 16 + grow) * GD_DIM + goff;
  const unsigned short* elp = e_lo + (size_t)(bm * 128 + wv * 16 + grow) * GD_DIM + goff;
  const unsigned short* dhp = wdh + (size_t)(bn * 128 + wv * 16 + grow) * GD_DIM + goff;
  const unsigned short* dlp = wdl + (size_t)(bn * 128 + wv * 16 + grow) * GD_DIM + goff;
  const unsigned short* uhp = wuh + (size_t)(bn * 128 + wv * 16 + grow) * GD_DIM + goff;
  const unsigned short* ulp = wul + (size_t)(bn * 128 + wv * 16 + grow) * GD_DIM + goff;
  const int ldst = (wv * 16) * 32;               // this wave's 16-row chunk (lds elems)

  const int fr = lane & 15;
  const int sw8 = ((lane >> 4) ^ ((lane >> 1) & 3)) * 8;

  f32x4 accD[4][2], accU[4][2];
#pragma unroll
  for (int m = 0; m < 4; ++m)
#pragma unroll
    for (int n = 0; n < 2; ++n) {
      accD[m][n] = (f32x4){0.f, 0.f, 0.f, 0.f};
      accU[m][n] = (f32x4){0.f, 0.f, 0.f, 0.f};
    }

#define STAGE7(t_) if ((t_) < 8) { const int b_ = (t_) % 3; const int kt_ = (t_) * 32; \
    async_copy16(ehp + kt_, &L[b_][0][ldst]); \
    async_copy16(elp + kt_, &L[b_][1][ldst]); \
    async_copy16(dhp + kt_, &L[b_][2][ldst]); \
    async_copy16(dlp + kt_, &L[b_][3][ldst]); \
    async_copy16(uhp + kt_, &L[b_][4][ldst]); \
    async_copy16(ulp + kt_, &L[b_][5][ldst]); }

  STAGE7(0); STAGE7(1);
  asm volatile("s_waitcnt vmcnt(6)" ::: "memory");
  __builtin_amdgcn_s_barrier();

#pragma unroll 1
  for (int t = 0; t < 8; ++t) {
    const int b = t % 3;
    bf16x8 fah[4], fal[4], fh[2], fl[2];
    // ---- phase 1: D-quadrant ----
#pragma unroll
    for (int m = 0; m < 4; ++m) {
      int off = (wm * 64 + m * 16 + fr) * 32 + sw8;
      fah[m] = *(const bf16x8*)&L[b][0][off];
      fal[m] = *(const bf16x8*)&L[b][1][off];
    }
#pragma unroll
    for (int n = 0; n < 2; ++n) {
      int off = (wn * 32 + n * 16 + fr) * 32 + sw8;
      fh[n] = *(const bf16x8*)&L[b][2][off];
      fl[n] = *(const bf16x8*)&L[b][3][off];
    }
    STAGE7(t + 2);
    __builtin_amdgcn_s_barrier();
    asm volatile("s_waitcnt lgkmcnt(0)" ::: "memory");
    __builtin_amdgcn_sched_barrier(0);
    __builtin_amdgcn_s_setprio(1);
#pragma unroll
    for (int m = 0; m < 4; ++m)
#pragma unroll
      for (int n = 0; n < 2; ++n) {
        accD[m][n] = __builtin_amdgcn_mfma_f32_16x16x32_bf16(fah[m], fh[n], accD[m][n], 0, 0, 0);
        accD[m][n] = __builtin_amdgcn_mfma_f32_16x16x32_bf16(fah[m], fl[n], accD[m][n], 0, 0, 0);
        accD[m][n] = __builtin_amdgcn_mfma_f32_16x16x32_bf16(fal[m], fh[n], accD[m][n], 0, 0, 0);
      }
    __builtin_amdgcn_s_setprio(0);
    __builtin_amdgcn_s_barrier();
    // ---- phase 2: U-quadrant (fah/fal reused) ----
#pragma unroll
    for (int n = 0; n < 2; ++n) {
      int off = (wn * 32 + n * 16 + fr) * 32 + sw8;
      fh[n] = *(const bf16x8*)&L[b][4][off];
      fl[n] = *(const bf16x8*)&L[b][5][off];
    }
    __builtin_amdgcn_s_barrier();
    asm volatile("s_waitcnt lgkmcnt(0)" ::: "memory");
    __builtin_amdgcn_sched_barrier(0);
    __builtin_amdgcn_s_setprio(1);
#pragma unroll
    for (int m = 0; m < 4; ++m)
#pragma unroll
      for (int n = 0; n < 2; ++n) {
        accU[m][n] = __builtin_amdgcn_mfma_f32_16x16x32_bf16(fah[m], fh[n], accU[m][n], 0, 0, 0);
        accU[m][n] = __builtin_amdgcn_mfma_f32_16x16x32_bf16(fah[m], fl[n], accU[m][n], 0, 0, 0);
        accU[m][n] = __builtin_amdgcn_mfma_f32_16x16x32_bf16(fal[m], fh[n], accU[m][n], 0, 0, 0);
      }
    __builtin_amdgcn_s_setprio(0);
    if (t <= 5)      { asm volatile("s_waitcnt vmcnt(6)" ::: "memory"); }
    else if (t == 6) { asm volatile("s_waitcnt vmcnt(0)" ::: "memory"); }
    __builtin_amdgcn_s_barrier();
  }
#undef STAGE7

  float sc = scale_p[0];
#pragma unroll
  for (int m = 0; m < 4; ++m)
#pragma unroll
    for (int j = 0; j < 4; ++j) {
      int token = bm * 128 + wm * 64 + m * 16 + (lane >> 4) * 4 + j;
      float rr = r[token];
#pragma unroll
      for (int n = 0; n < 2; ++n) {
        int d = bn * 128 + wn * 32 + n * 16 + fr;
        float xn = x[(size_t)token * D_DIM + d] * rr * nw[d];
        out[(size_t)token * D_DIM + d] = tanhf(accD[m][n][j]) * xn * accU[m][n][j] * sc;
      }
    }
}

extern "C" void kernel_launch(void* const* d_in, const int* in_sizes, int n_in,
                              void* d_out, int out_size, void* d_ws, size_t ws_size,
                              hipStream_t stream) {
  const float* x       = (const float*)d_in[0];
  const float* Wc      = (const float*)d_in[1];
  const float* temp    = (const float*)d_in[2];
  const float* genes   = (const float*)d_in[3];
  const float* Wd      = (const float*)d_in[4];
  const float* Wu      = (const float*)d_in[5];
  const float* nw      = (const float*)d_in[6];
  const float* scale_p = (const float*)d_in[7];

  char* ws = (char*)d_ws;
  float* r_buf          = (float*)ws;                                   // 32 KB (64 KB reserved)
  unsigned short* xn_bf = (unsigned short*)(ws + 65536);                // 32 MB (free after k3)
  unsigned short* wc_bf = (unsigned short*)(ws + 65536 + (size_t)M_TOK * D_DIM * 2);   // 16 MB
  char* p = ws + 65536 + (size_t)M_TOK * D_DIM * 2 + (size_t)G_GENES * D_DIM * 2;
  int* cand    = (int*)p;                       p += (size_t)M_TOK * NCAND * 4;
  p += (size_t)M_TOK * NCAND * 8;               // (former cval slot, unused)
  unsigned short* e_hi = (unsigned short*)p;    p += (size_t)M_TOK * GD_DIM * 2;
  unsigned short* e_lo = (unsigned short*)p;

  // Wd/Wu bf16 hi/lo splits live in the xn_bf region (dead after k3): 4 x 1 MB
  unsigned short* wdh = (unsigned short*)(ws + 65536);
  unsigned short* wdl = wdh + (size_t)D_DIM * GD_DIM;
  unsigned short* wuh = wdl + (size_t)D_DIM * GD_DIM;
  unsigned short* wul = wuh + (size_t)D_DIM * GD_DIM;
  // fp64 partials also in the dead xn_bf region, after the 4 MB of splits:
  double* part = (double*)(ws + 65536 + 4ull * D_DIM * GD_DIM * 2);

  unsigned short* logits_bf = (unsigned short*)d_out;  // 33.5M bf16 == 64 MB == d_out

  k1_rmsnorm<<<dim3(M_TOK), dim3(256), 0, stream>>>(x, nw, r_buf, xn_bf);
  k2_cvt<<<dim3((G_GENES * D_DIM) / (256 * 8)), dim3(256), 0, stream>>>(Wc, wc_bf);
  k3_gemm_logits<<<dim3((M_TOK / 256) * (G_GENES / 256)), dim3(512), 0, stream>>>(xn_bf, wc_bf, logits_bf);
  k4_topk<<<dim3(M_TOK / 4), dim3(256), 0, stream>>>(logits_bf, cand);
  k2b_split<<<dim3((D_DIM * GD_DIM) / (256 * 4), 2), dim3(256), 0, stream>>>(Wd, Wu, wdh, wdl, wuh, wul);
  k5a_partial<<<dim3(M_TOK), dim3(256), 0, stream>>>(x, r_buf, nw, Wc, cand, part);
  k6_express<<<dim3(M_TOK), dim3(256), 0, stream>>>(part, cand, genes, temp, e_hi, e_lo);
  k7_mfma<<<dim3((M_TOK / 128) * (D_DIM / 128)), dim3(512), 0, stream>>>(e_hi, e_lo, wdh, wdl, wuh, wul,
                                                                         x, r_buf, nw, scale_p, (float*)d_out);
}